// Round 1
// baseline (551.627 us; speedup 1.0000x reference)
//
#include <hip/hip_runtime.h>
#include <hip/hip_bf16.h>

#define N_NODES 50000
#define N_EDGES 600000
#define HID     128
#define NG      500
#define NB_SCAN 196   // ceil(50000/256)

// ---------------- CSR build ----------------

__global__ void k_count(const int* __restrict__ dst, int* __restrict__ cnt) {
    int e = blockIdx.x * 256 + threadIdx.x;
    if (e < N_EDGES) atomicAdd(&cnt[dst[e]], 1);
}

__global__ void k_blocksum(const int* __restrict__ cnt, int* __restrict__ bsum) {
    __shared__ int s[256];
    int i = blockIdx.x * 256 + threadIdx.x;
    s[threadIdx.x] = (i < N_NODES) ? cnt[i] : 0;
    __syncthreads();
    for (int o = 128; o; o >>= 1) {
        if (threadIdx.x < o) s[threadIdx.x] += s[threadIdx.x + o];
        __syncthreads();
    }
    if (threadIdx.x == 0) bsum[blockIdx.x] = s[0];
}

__global__ void k_scanbsum(int* __restrict__ bsum) {
    if (blockIdx.x == 0 && threadIdx.x == 0) {
        int run = 0;
        for (int b = 0; b < NB_SCAN; b++) { int t = bsum[b]; bsum[b] = run; run += t; }
    }
}

__global__ void k_rowptr(const int* __restrict__ cnt, const int* __restrict__ bsum,
                         int* __restrict__ rowptr, float* __restrict__ dinv) {
    __shared__ int s[256];
    int i = blockIdx.x * 256 + threadIdx.x;
    int c = (i < N_NODES) ? cnt[i] : 0;
    s[threadIdx.x] = c;
    __syncthreads();
    // Hillis-Steele inclusive scan
    for (int o = 1; o < 256; o <<= 1) {
        int v = (threadIdx.x >= o) ? s[threadIdx.x - o] : 0;
        __syncthreads();
        s[threadIdx.x] += v;
        __syncthreads();
    }
    if (i < N_NODES) {
        int incl = s[threadIdx.x];
        rowptr[i] = bsum[blockIdx.x] + incl - c;
        dinv[i] = rsqrtf((float)c + 1.0f);
        if (i == N_NODES - 1) rowptr[N_NODES] = bsum[blockIdx.x] + incl;
    }
}

__global__ void k_fill(const int* __restrict__ src, const int* __restrict__ dst,
                       const int* __restrict__ rowptr, int* __restrict__ cnt,
                       int* __restrict__ csr) {
    int e = blockIdx.x * 256 + threadIdx.x;
    if (e < N_EDGES) {
        int d = dst[e];
        int pos = atomicAdd(&cnt[d], 1);
        csr[rowptr[d] + pos] = src[e];
    }
}

// ---------------- Layer 1 feature transform: h[i][c] = x[i] * W1[c] ----------------

__global__ void k_xw1(const float* __restrict__ x, const float* __restrict__ W1,
                      float* __restrict__ h) {
    int idx = blockIdx.x * 256 + threadIdx.x;
    if (idx < N_NODES * HID) h[idx] = x[idx >> 7] * W1[idx & 127];
}

// ---------------- Dense GEMM: O[M,128] = H[M,128] @ W[128,128] ----------------
// grid = (ceil(M/32), 2); block = 256. W half (128x64) in LDS, 32-row H tile in LDS.
// Each thread: 2 rows x 4 cols (float4), 8 FMA per k-iter.

__global__ __launch_bounds__(256) void k_gemm(const float* __restrict__ H,
                                              const float* __restrict__ W,
                                              float* __restrict__ O) {
    __shared__ float Ws[128 * 64];      // 32 KB
    __shared__ float Hs[32 * 132];      // 16.5 KB, stride 132 breaks bank conflicts
    int t  = threadIdx.x;
    int n0 = blockIdx.y * 64;
    int r0 = blockIdx.x * 32;

    // stage W half: 8192 floats / 256 threads = 8 x float4
    for (int p = 0; p < 8; p++) {
        int elem = t * 4 + p * 1024;
        int r = elem >> 6, cc = elem & 63;
        *(float4*)&Ws[elem] = *(const float4*)&W[r * 128 + n0 + cc];
    }
    // stage H tile: 4096 floats / 256 threads = 4 x float4
    for (int p = 0; p < 4; p++) {
        int elem = t * 4 + p * 1024;
        int r = elem >> 7, cc = elem & 127;
        float4 v = {0.f, 0.f, 0.f, 0.f};
        if (r0 + r < N_NODES) v = *(const float4*)&H[(size_t)(r0 + r) * HID + cc];
        *(float4*)&Hs[r * 132 + cc] = v;
    }
    __syncthreads();

    int col  = (t & 15) * 4;
    int row0 = (t >> 4) * 2;
    float4 a0 = {0.f, 0.f, 0.f, 0.f}, a1 = {0.f, 0.f, 0.f, 0.f};
    for (int k = 0; k < 128; k++) {
        float4 w = *(float4*)&Ws[k * 64 + col];
        float h0 = Hs[row0 * 132 + k];
        float h1 = Hs[(row0 + 1) * 132 + k];
        a0.x += h0 * w.x; a0.y += h0 * w.y; a0.z += h0 * w.z; a0.w += h0 * w.w;
        a1.x += h1 * w.x; a1.y += h1 * w.y; a1.z += h1 * w.z; a1.w += h1 * w.w;
    }
    if (r0 + row0 < N_NODES) {
        *(float4*)&O[(size_t)(r0 + row0) * HID + n0 + col]     = a0;
        *(float4*)&O[(size_t)(r0 + row0 + 1) * HID + n0 + col] = a1;
    }
}

// ---------------- Aggregation: one block (128 threads) per node ----------------

__global__ __launch_bounds__(128) void k_agg(const float* __restrict__ H,
                                             const int* __restrict__ rowptr,
                                             const int* __restrict__ csr,
                                             const float* __restrict__ dinv,
                                             const float* __restrict__ bias,
                                             float* __restrict__ out, int relu) {
    int i = blockIdx.x;
    int c = threadIdx.x;
    float di  = dinv[i];
    float acc = H[(size_t)i * HID + c] * di * di;   // self-loop
    int e0 = rowptr[i], e1 = rowptr[i + 1];
    for (int e = e0; e < e1; e++) {
        int s = csr[e];
        acc += H[(size_t)s * HID + c] * (dinv[s] * di);
    }
    float v = acc + bias[c];
    if (relu) v = fmaxf(v, 0.f);
    out[(size_t)i * HID + c] = v;
}

// ---------------- Pooling ----------------

__global__ void k_pool(const float* __restrict__ h, const int* __restrict__ batch,
                       float* __restrict__ pool, float* __restrict__ gcnt) {
    int idx = blockIdx.x * 256 + threadIdx.x;
    if (idx < N_NODES * HID) {
        int node = idx >> 7, c = idx & 127;
        int g = batch[node];
        atomicAdd(&pool[g * HID + c], h[idx]);
        if (c == 0) atomicAdd(&gcnt[g], 1.0f);
    }
}

__global__ void k_final(const float* __restrict__ pool, const float* __restrict__ gcnt,
                        const float* __restrict__ Wlin, const float* __restrict__ blin,
                        float* __restrict__ out) {
    int g = blockIdx.x;
    int lane = threadIdx.x;   // 64 threads
    float inv = 1.0f / fmaxf(gcnt[g], 1.0f);
    float v0 = pool[g * HID + lane] * inv;
    float v1 = pool[g * HID + 64 + lane] * inv;
    float s0 = v0 * Wlin[lane * 2 + 0] + v1 * Wlin[(lane + 64) * 2 + 0];
    float s1 = v0 * Wlin[lane * 2 + 1] + v1 * Wlin[(lane + 64) * 2 + 1];
    for (int o = 32; o; o >>= 1) { s0 += __shfl_down(s0, o); s1 += __shfl_down(s1, o); }
    if (lane == 0) {
        out[g * 2 + 0] = s0 + blin[0];
        out[g * 2 + 1] = s1 + blin[1];
    }
}

// ---------------- launch ----------------

extern "C" void kernel_launch(void* const* d_in, const int* in_sizes, int n_in,
                              void* d_out, int out_size, void* d_ws, size_t ws_size,
                              hipStream_t stream) {
    const float* x    = (const float*)d_in[0];
    const float* W1   = (const float*)d_in[1];
    const float* b1   = (const float*)d_in[2];
    const float* W2   = (const float*)d_in[3];
    const float* b2   = (const float*)d_in[4];
    const float* W3   = (const float*)d_in[5];
    const float* b3   = (const float*)d_in[6];
    const float* Wlin = (const float*)d_in[7];
    const float* blin = (const float*)d_in[8];
    const int*   eidx = (const int*)d_in[9];
    const int*   batch= (const int*)d_in[10];
    const int* esrc = eidx;
    const int* edst = eidx + N_EDGES;
    float* out = (float*)d_out;

    char* w = (char*)d_ws;
    size_t off = 0;
    auto alloc = [&](size_t bytes) { size_t o = off; off = (off + bytes + 255) & ~(size_t)255; return o; };
    int*   cnt    = (int*)  (w + alloc(N_NODES * 4));
    int*   rowptr = (int*)  (w + alloc((N_NODES + 1) * 4));
    int*   csr    = (int*)  (w + alloc(N_EDGES * 4));
    float* dinv   = (float*)(w + alloc(N_NODES * 4));
    int*   bsum   = (int*)  (w + alloc(NB_SCAN * 4));
    float* hA     = (float*)(w + alloc((size_t)N_NODES * HID * 4));
    float* hB     = (float*)(w + alloc((size_t)N_NODES * HID * 4));
    float* pool   = (float*)(w + alloc(NG * HID * 4));
    float* gcnt   = (float*)(w + alloc(NG * 4));

    const int EB = (N_EDGES + 255) / 256;      // 2344
    const int FB = (N_NODES * HID + 255) / 256; // 25000

    // CSR + degrees
    hipMemsetAsync(cnt, 0, N_NODES * 4, stream);
    k_count<<<EB, 256, 0, stream>>>(edst, cnt);
    k_blocksum<<<NB_SCAN, 256, 0, stream>>>(cnt, bsum);
    k_scanbsum<<<1, 64, 0, stream>>>(bsum);
    k_rowptr<<<NB_SCAN, 256, 0, stream>>>(cnt, bsum, rowptr, dinv);
    hipMemsetAsync(cnt, 0, N_NODES * 4, stream);
    k_fill<<<EB, 256, 0, stream>>>(esrc, edst, rowptr, cnt, csr);

    dim3 gg((N_NODES + 31) / 32, 2);

    // Layer 1
    k_xw1<<<FB, 256, 0, stream>>>(x, W1, hA);
    k_agg<<<N_NODES, 128, 0, stream>>>(hA, rowptr, csr, dinv, b1, hB, 1);
    // Layer 2
    k_gemm<<<gg, 256, 0, stream>>>(hB, W2, hA);
    k_agg<<<N_NODES, 128, 0, stream>>>(hA, rowptr, csr, dinv, b2, hB, 1);
    // Layer 3
    k_gemm<<<gg, 256, 0, stream>>>(hB, W3, hA);
    k_agg<<<N_NODES, 128, 0, stream>>>(hA, rowptr, csr, dinv, b3, hB, 0);

    // Pool + head
    hipMemsetAsync(pool, 0, NG * HID * 4, stream);
    hipMemsetAsync(gcnt, 0, NG * 4, stream);
    k_pool<<<FB, 256, 0, stream>>>(hB, batch, pool, gcnt);
    k_final<<<NG, 64, 0, stream>>>(pool, gcnt, Wlin, blin, out);
}

// Round 2
// 384.156 us; speedup vs baseline: 1.4359x; 1.4359x over previous
//
#include <hip/hip_runtime.h>
#include <hip/hip_bf16.h>

#define N_NODES 50000
#define N_EDGES 600000
#define HID     128
#define NG      500
#define NB_SCAN 196   // ceil(50000/256)

// ---------------- CSR build ----------------

__global__ void k_count(const int* __restrict__ dst, int* __restrict__ cnt) {
    int e = blockIdx.x * 256 + threadIdx.x;
    if (e < N_EDGES) atomicAdd(&cnt[dst[e]], 1);
}

__global__ void k_blocksum(const int* __restrict__ cnt, int* __restrict__ bsum) {
    __shared__ int s[256];
    int i = blockIdx.x * 256 + threadIdx.x;
    s[threadIdx.x] = (i < N_NODES) ? cnt[i] : 0;
    __syncthreads();
    for (int o = 128; o; o >>= 1) {
        if (threadIdx.x < o) s[threadIdx.x] += s[threadIdx.x + o];
        __syncthreads();
    }
    if (threadIdx.x == 0) bsum[blockIdx.x] = s[0];
}

// 196-entry exclusive scan by one wave (each lane owns 4 entries)
__global__ void k_scanbsum(int* __restrict__ bsum) {
    int lane = threadIdx.x;            // 64 lanes
    int v[4];
    int base = lane * 4;
    for (int j = 0; j < 4; j++) v[j] = (base + j < NB_SCAN) ? bsum[base + j] : 0;
    int tot = v[0] + v[1] + v[2] + v[3];
    // inclusive wave scan of tot
    int inc = tot;
    for (int o = 1; o < 64; o <<= 1) {
        int u = __shfl_up(inc, o);
        if (lane >= o) inc += u;
    }
    int excl = inc - tot;              // exclusive prefix for this lane's chunk
    int run = excl;
    for (int j = 0; j < 4; j++) {
        if (base + j < NB_SCAN) bsum[base + j] = run;
        run += v[j];
    }
}

__global__ void k_rowptr(const int* __restrict__ cnt, const int* __restrict__ bsum,
                         int* __restrict__ rowptr, float* __restrict__ dinv) {
    __shared__ int s[256];
    int i = blockIdx.x * 256 + threadIdx.x;
    int c = (i < N_NODES) ? cnt[i] : 0;
    s[threadIdx.x] = c;
    __syncthreads();
    for (int o = 1; o < 256; o <<= 1) {
        int v = (threadIdx.x >= o) ? s[threadIdx.x - o] : 0;
        __syncthreads();
        s[threadIdx.x] += v;
        __syncthreads();
    }
    if (i < N_NODES) {
        int incl = s[threadIdx.x];
        rowptr[i] = bsum[blockIdx.x] + incl - c;
        dinv[i] = rsqrtf((float)c + 1.0f);
        if (i == N_NODES - 1) rowptr[N_NODES] = bsum[blockIdx.x] + incl;
    }
}

__global__ void k_fill(const int* __restrict__ src, const int* __restrict__ dst,
                       const int* __restrict__ rowptr, int* __restrict__ cnt,
                       int* __restrict__ csr) {
    int e = blockIdx.x * 256 + threadIdx.x;
    if (e < N_EDGES) {
        int d = dst[e];
        int pos = atomicAdd(&cnt[d], 1);
        csr[rowptr[d] + pos] = src[e];
    }
}

// ---------------- Layer 1 (rank-1): scalar aggregate of x, then outer product ----------------

__global__ void k_agg1(const float* __restrict__ x, const int* __restrict__ rowptr,
                       const int* __restrict__ csr, const float* __restrict__ dinv,
                       float* __restrict__ s1) {
    int i = blockIdx.x * 256 + threadIdx.x;
    if (i < N_NODES) {
        float di = dinv[i];
        float acc = x[i] * di * di;
        int e0 = rowptr[i], e1 = rowptr[i + 1];
        for (int e = e0; e < e1; e++) {
            int s = csr[e];
            acc += x[s] * dinv[s] * di;
        }
        s1[i] = acc;
    }
}

__global__ void k_outer(const float* __restrict__ s1, const float* __restrict__ W1,
                        const float* __restrict__ b1, float* __restrict__ h) {
    int idx = blockIdx.x * 256 + threadIdx.x;   // one float4 per thread
    if (idx < N_NODES * 32) {
        int node = idx >> 5, c4 = idx & 31;
        float s = s1[node];
        float4 w = ((const float4*)W1)[c4];
        float4 b = ((const float4*)b1)[c4];
        float4 v;
        v.x = fmaxf(s * w.x + b.x, 0.f);
        v.y = fmaxf(s * w.y + b.y, 0.f);
        v.z = fmaxf(s * w.z + b.z, 0.f);
        v.w = fmaxf(s * w.w + b.w, 0.f);
        ((float4*)h)[idx] = v;
    }
}

// ---------------- Dense GEMM: O[M,128] = H[M,128] @ W[128,128] ----------------
// grid = (ceil(M/64), 2); block = 256. 64x64 output tile, 4x4 per thread,
// H tile stored TRANSPOSED in LDS so both operands load as b128.

__global__ __launch_bounds__(256) void k_gemm(const float* __restrict__ H,
                                              const float* __restrict__ W,
                                              float* __restrict__ O) {
    __shared__ float Ws[128 * 64];     // 32 KB
    __shared__ float HsT[128 * 64];    // 32 KB, [k][r]
    int t  = threadIdx.x;
    int n0 = blockIdx.y * 64;
    int r0 = blockIdx.x * 64;

    for (int p = 0; p < 8; p++) {
        int elem = t * 4 + p * 1024;
        int k = elem >> 6, cc = elem & 63;
        *(float4*)&Ws[elem] = *(const float4*)&W[k * 128 + n0 + cc];
    }
    for (int p = 0; p < 8; p++) {
        int elem = t * 4 + p * 1024;   // 8192 floats = 64 rows x 128
        int r = elem >> 7, cc = elem & 127;
        float4 v = {0.f, 0.f, 0.f, 0.f};
        if (r0 + r < N_NODES) v = *(const float4*)&H[(size_t)(r0 + r) * HID + cc];
        HsT[(cc + 0) * 64 + r] = v.x;
        HsT[(cc + 1) * 64 + r] = v.y;
        HsT[(cc + 2) * 64 + r] = v.z;
        HsT[(cc + 3) * 64 + r] = v.w;
    }
    __syncthreads();

    int col = (t & 15) * 4;
    int row = (t >> 4) * 4;
    float acc[4][4] = {};
    #pragma unroll 4
    for (int k = 0; k < 128; k++) {
        float4 w = *(float4*)&Ws[k * 64 + col];
        float4 h = *(float4*)&HsT[k * 64 + row];
        acc[0][0] += h.x * w.x; acc[0][1] += h.x * w.y; acc[0][2] += h.x * w.z; acc[0][3] += h.x * w.w;
        acc[1][0] += h.y * w.x; acc[1][1] += h.y * w.y; acc[1][2] += h.y * w.z; acc[1][3] += h.y * w.w;
        acc[2][0] += h.z * w.x; acc[2][1] += h.z * w.y; acc[2][2] += h.z * w.z; acc[2][3] += h.z * w.w;
        acc[3][0] += h.w * w.x; acc[3][1] += h.w * w.y; acc[3][2] += h.w * w.z; acc[3][3] += h.w * w.w;
    }
    for (int r = 0; r < 4; r++) {
        int rr = r0 + row + r;
        if (rr < N_NODES) {
            float4 v = {acc[r][0], acc[r][1], acc[r][2], acc[r][3]};
            *(float4*)&O[(size_t)rr * HID + n0 + col] = v;
        }
    }
}

// ---------------- Aggregation: float4 channels, 8 nodes per 256-thread block ----------------

__global__ __launch_bounds__(256) void k_agg(const float* __restrict__ H,
                                             const int* __restrict__ rowptr,
                                             const int* __restrict__ csr,
                                             const float* __restrict__ dinv,
                                             const float* __restrict__ bias,
                                             float* __restrict__ out, int relu) {
    int node = blockIdx.x * 8 + (threadIdx.x >> 5);
    int c4   = threadIdx.x & 31;
    if (node >= N_NODES) return;
    const float4* H4 = (const float4*)H;
    float di = dinv[node];
    float4 h = H4[(size_t)node * 32 + c4];
    float w0 = di * di;
    float4 acc = {h.x * w0, h.y * w0, h.z * w0, h.w * w0};
    int e0 = rowptr[node], e1 = rowptr[node + 1];
    int e = e0;
    for (; e + 1 < e1; e += 2) {
        int s0 = csr[e], s1 = csr[e + 1];
        float wa = dinv[s0] * di, wb = dinv[s1] * di;
        float4 ha = H4[(size_t)s0 * 32 + c4];
        float4 hb = H4[(size_t)s1 * 32 + c4];
        acc.x += ha.x * wa + hb.x * wb;
        acc.y += ha.y * wa + hb.y * wb;
        acc.z += ha.z * wa + hb.z * wb;
        acc.w += ha.w * wa + hb.w * wb;
    }
    if (e < e1) {
        int s0 = csr[e];
        float wa = dinv[s0] * di;
        float4 ha = H4[(size_t)s0 * 32 + c4];
        acc.x += ha.x * wa; acc.y += ha.y * wa; acc.z += ha.z * wa; acc.w += ha.w * wa;
    }
    float4 b = ((const float4*)bias)[c4];
    float4 v = {acc.x + b.x, acc.y + b.y, acc.z + b.z, acc.w + b.w};
    if (relu) {
        v.x = fmaxf(v.x, 0.f); v.y = fmaxf(v.y, 0.f);
        v.z = fmaxf(v.z, 0.f); v.w = fmaxf(v.w, 0.f);
    }
    ((float4*)out)[(size_t)node * 32 + c4] = v;
}

// ---------------- Fused pool + head: batch is SORTED -> binary-search segments ----------------

__global__ __launch_bounds__(128) void k_pool_head(const float* __restrict__ h,
                                                   const int* __restrict__ batch,
                                                   const float* __restrict__ Wlin,
                                                   const float* __restrict__ blin,
                                                   float* __restrict__ out) {
    int g = blockIdx.x;
    int t = threadIdx.x;   // 128 threads, one channel each
    // lower_bound(batch, g) and lower_bound(batch, g+1)
    int lo = 0, hi = N_NODES;
    while (lo < hi) { int mid = (lo + hi) >> 1; if (batch[mid] < g) lo = mid + 1; else hi = mid; }
    int start = lo;
    hi = N_NODES;
    while (lo < hi) { int mid = (lo + hi) >> 1; if (batch[mid] < g + 1) lo = mid + 1; else hi = mid; }
    int end = lo;

    float acc = 0.f;
    int n = start;
    for (; n + 1 < end; n += 2)
        acc += h[(size_t)n * HID + t] + h[(size_t)(n + 1) * HID + t];
    if (n < end) acc += h[(size_t)n * HID + t];

    float inv = 1.0f / fmaxf((float)(end - start), 1.0f);
    float pooled = acc * inv;
    float p0 = pooled * Wlin[t * 2 + 0];
    float p1 = pooled * Wlin[t * 2 + 1];
    for (int o = 32; o; o >>= 1) { p0 += __shfl_down(p0, o); p1 += __shfl_down(p1, o); }
    __shared__ float r0s[2], r1s[2];
    int w = t >> 6;
    if ((t & 63) == 0) { r0s[w] = p0; r1s[w] = p1; }
    __syncthreads();
    if (t == 0) {
        out[g * 2 + 0] = r0s[0] + r0s[1] + blin[0];
        out[g * 2 + 1] = r1s[0] + r1s[1] + blin[1];
    }
}

// ---------------- launch ----------------

extern "C" void kernel_launch(void* const* d_in, const int* in_sizes, int n_in,
                              void* d_out, int out_size, void* d_ws, size_t ws_size,
                              hipStream_t stream) {
    const float* x    = (const float*)d_in[0];
    const float* W1   = (const float*)d_in[1];
    const float* b1   = (const float*)d_in[2];
    const float* W2   = (const float*)d_in[3];
    const float* b2   = (const float*)d_in[4];
    const float* W3   = (const float*)d_in[5];
    const float* b3   = (const float*)d_in[6];
    const float* Wlin = (const float*)d_in[7];
    const float* blin = (const float*)d_in[8];
    const int*   eidx = (const int*)d_in[9];
    const int*   batch= (const int*)d_in[10];
    const int* esrc = eidx;
    const int* edst = eidx + N_EDGES;
    float* out = (float*)d_out;

    char* w = (char*)d_ws;
    size_t off = 0;
    auto alloc = [&](size_t bytes) { size_t o = off; off = (off + bytes + 255) & ~(size_t)255; return o; };
    int*   cnt    = (int*)  (w + alloc(N_NODES * 4));
    int*   rowptr = (int*)  (w + alloc((N_NODES + 1) * 4));
    int*   csr    = (int*)  (w + alloc(N_EDGES * 4));
    float* dinv   = (float*)(w + alloc(N_NODES * 4));
    int*   bsum   = (int*)  (w + alloc(NB_SCAN * 4));
    float* s1     = (float*)(w + alloc(N_NODES * 4));
    float* hA     = (float*)(w + alloc((size_t)N_NODES * HID * 4));
    float* hB     = (float*)(w + alloc((size_t)N_NODES * HID * 4));

    const int EB = (N_EDGES + 255) / 256;       // 2344
    const int NB = (N_NODES + 255) / 256;       // 196

    // CSR + degrees
    hipMemsetAsync(cnt, 0, N_NODES * 4, stream);
    k_count<<<EB, 256, 0, stream>>>(edst, cnt);
    k_blocksum<<<NB_SCAN, 256, 0, stream>>>(cnt, bsum);
    k_scanbsum<<<1, 64, 0, stream>>>(bsum);
    k_rowptr<<<NB_SCAN, 256, 0, stream>>>(cnt, bsum, rowptr, dinv);
    hipMemsetAsync(cnt, 0, N_NODES * 4, stream);
    k_fill<<<EB, 256, 0, stream>>>(esrc, edst, rowptr, cnt, csr);

    dim3 gg((N_NODES + 63) / 64, 2);
    const int AB = (N_NODES + 7) / 8;           // 6250

    // Layer 1 (rank-1 shortcut)
    k_agg1<<<NB, 256, 0, stream>>>(x, rowptr, csr, dinv, s1);
    k_outer<<<(N_NODES * 32 + 255) / 256, 256, 0, stream>>>(s1, W1, b1, hB);
    // Layer 2
    k_gemm<<<gg, 256, 0, stream>>>(hB, W2, hA);
    k_agg<<<AB, 256, 0, stream>>>(hA, rowptr, csr, dinv, b2, hB, 1);
    // Layer 3
    k_gemm<<<gg, 256, 0, stream>>>(hB, W3, hA);
    k_agg<<<AB, 256, 0, stream>>>(hA, rowptr, csr, dinv, b3, hB, 0);

    // Fused pool + head
    k_pool_head<<<NG, 128, 0, stream>>>(hB, batch, Wlin, blin, out);
}

// Round 3
// 354.633 us; speedup vs baseline: 1.5555x; 1.0832x over previous
//
#include <hip/hip_runtime.h>
#include <hip/hip_bf16.h>

#define N_NODES 50000
#define N_EDGES 600000
#define HID     128
#define NG      500
#define NB_SCAN 196   // ceil(50000/256)

// ---------------- CSR build ----------------

__global__ void k_count(const int* __restrict__ dst, int* __restrict__ cnt) {
    int e = blockIdx.x * 256 + threadIdx.x;
    if (e < N_EDGES) atomicAdd(&cnt[dst[e]], 1);
}

__global__ void k_blocksum(const int* __restrict__ cnt, int* __restrict__ bsum) {
    __shared__ int s[256];
    int i = blockIdx.x * 256 + threadIdx.x;
    s[threadIdx.x] = (i < N_NODES) ? cnt[i] : 0;
    __syncthreads();
    for (int o = 128; o; o >>= 1) {
        if (threadIdx.x < o) s[threadIdx.x] += s[threadIdx.x + o];
        __syncthreads();
    }
    if (threadIdx.x == 0) bsum[blockIdx.x] = s[0];
}

// 196-entry exclusive scan by one wave (each lane owns 4 entries)
__global__ void k_scanbsum(int* __restrict__ bsum) {
    int lane = threadIdx.x;            // 64 lanes
    int v[4];
    int base = lane * 4;
    for (int j = 0; j < 4; j++) v[j] = (base + j < NB_SCAN) ? bsum[base + j] : 0;
    int tot = v[0] + v[1] + v[2] + v[3];
    int inc = tot;
    for (int o = 1; o < 64; o <<= 1) {
        int u = __shfl_up(inc, o);
        if (lane >= o) inc += u;
    }
    int excl = inc - tot;
    int run = excl;
    for (int j = 0; j < 4; j++) {
        if (base + j < NB_SCAN) bsum[base + j] = run;
        run += v[j];
    }
}

__global__ void k_rowptr(const int* __restrict__ cnt, const int* __restrict__ bsum,
                         int* __restrict__ rowptr, float* __restrict__ dinv) {
    __shared__ int s[256];
    int i = blockIdx.x * 256 + threadIdx.x;
    int c = (i < N_NODES) ? cnt[i] : 0;
    s[threadIdx.x] = c;
    __syncthreads();
    for (int o = 1; o < 256; o <<= 1) {
        int v = (threadIdx.x >= o) ? s[threadIdx.x - o] : 0;
        __syncthreads();
        s[threadIdx.x] += v;
        __syncthreads();
    }
    if (i < N_NODES) {
        int incl = s[threadIdx.x];
        rowptr[i] = bsum[blockIdx.x] + incl - c;
        dinv[i] = rsqrtf((float)c + 1.0f);
        if (i == N_NODES - 1) rowptr[N_NODES] = bsum[blockIdx.x] + incl;
    }
}

__global__ void k_fill(const int* __restrict__ src, const int* __restrict__ dst,
                       const int* __restrict__ rowptr, int* __restrict__ cnt,
                       int* __restrict__ csr) {
    int e = blockIdx.x * 256 + threadIdx.x;
    if (e < N_EDGES) {
        int d = dst[e];
        int pos = atomicAdd(&cnt[d], 1);
        csr[rowptr[d] + pos] = src[e];
    }
}

// ---------------- Layer 1 (rank-1): scalar aggregate of x, then outer product ----------------

__global__ void k_agg1(const float* __restrict__ x, const int* __restrict__ rowptr,
                       const int* __restrict__ csr, const float* __restrict__ dinv,
                       float* __restrict__ s1) {
    int i = blockIdx.x * 256 + threadIdx.x;
    if (i < N_NODES) {
        float di = dinv[i];
        float acc = x[i] * di * di;
        int e0 = rowptr[i], e1 = rowptr[i + 1];
        for (int e = e0; e < e1; e++) {
            int s = csr[e];
            acc += x[s] * dinv[s] * di;
        }
        s1[i] = acc;
    }
}

__global__ void k_outer(const float* __restrict__ s1, const float* __restrict__ W1,
                        const float* __restrict__ b1, float* __restrict__ h) {
    int idx = blockIdx.x * 256 + threadIdx.x;   // one float4 per thread
    if (idx < N_NODES * 32) {
        int node = idx >> 5, c4 = idx & 31;
        float s = s1[node];
        float4 w = ((const float4*)W1)[c4];
        float4 b = ((const float4*)b1)[c4];
        float4 v;
        v.x = fmaxf(s * w.x + b.x, 0.f);
        v.y = fmaxf(s * w.y + b.y, 0.f);
        v.z = fmaxf(s * w.z + b.z, 0.f);
        v.w = fmaxf(s * w.w + b.w, 0.f);
        ((float4*)h)[idx] = v;
    }
}

// ---------------- Dense GEMM: O[M,128] = H[M,128] @ W[128,128] ----------------
// grid = (ceil(M/64), 2); block = 256. 64x64 output tile, 4x4 per thread.
// HsT leading dim padded to 65: transposed staging stores become 4-way
// (free-ish) instead of 32-way bank conflicts; compute reads stay broadcast.

#define HSTP 65

__global__ __launch_bounds__(256) void k_gemm(const float* __restrict__ H,
                                              const float* __restrict__ W,
                                              float* __restrict__ O) {
    __shared__ float Ws[128 * 64];       // 32 KB
    __shared__ float HsT[128 * HSTP];    // 33.3 KB, [k][r] padded
    int t  = threadIdx.x;
    int n0 = blockIdx.y * 64;
    int r0 = blockIdx.x * 64;

    for (int p = 0; p < 8; p++) {
        int elem = t * 4 + p * 1024;
        int k = elem >> 6, cc = elem & 63;
        *(float4*)&Ws[elem] = *(const float4*)&W[k * 128 + n0 + cc];
    }
    for (int p = 0; p < 8; p++) {
        int elem = t * 4 + p * 1024;   // 8192 floats = 64 rows x 128
        int r = elem >> 7, cc = elem & 127;
        float4 v = {0.f, 0.f, 0.f, 0.f};
        if (r0 + r < N_NODES) v = *(const float4*)&H[(size_t)(r0 + r) * HID + cc];
        HsT[(cc + 0) * HSTP + r] = v.x;
        HsT[(cc + 1) * HSTP + r] = v.y;
        HsT[(cc + 2) * HSTP + r] = v.z;
        HsT[(cc + 3) * HSTP + r] = v.w;
    }
    __syncthreads();

    int col = (t & 15) * 4;
    int row = (t >> 4) * 4;
    float acc[4][4] = {};
    #pragma unroll 4
    for (int k = 0; k < 128; k++) {
        float4 w = *(float4*)&Ws[k * 64 + col];
        float4 h = *(float4*)&HsT[k * HSTP + row];
        acc[0][0] += h.x * w.x; acc[0][1] += h.x * w.y; acc[0][2] += h.x * w.z; acc[0][3] += h.x * w.w;
        acc[1][0] += h.y * w.x; acc[1][1] += h.y * w.y; acc[1][2] += h.y * w.z; acc[1][3] += h.y * w.w;
        acc[2][0] += h.z * w.x; acc[2][1] += h.z * w.y; acc[2][2] += h.z * w.z; acc[2][3] += h.z * w.w;
        acc[3][0] += h.w * w.x; acc[3][1] += h.w * w.y; acc[3][2] += h.w * w.z; acc[3][3] += h.w * w.w;
    }
    for (int r = 0; r < 4; r++) {
        int rr = r0 + row + r;
        if (rr < N_NODES) {
            float4 v = {acc[r][0], acc[r][1], acc[r][2], acc[r][3]};
            *(float4*)&O[(size_t)rr * HID + n0 + col] = v;
        }
    }
}

// ---------------- Aggregation: float4 channels, 8 nodes per 256-thread block ----------------

__global__ __launch_bounds__(256) void k_agg(const float* __restrict__ H,
                                             const int* __restrict__ rowptr,
                                             const int* __restrict__ csr,
                                             const float* __restrict__ dinv,
                                             const float* __restrict__ bias,
                                             float* __restrict__ out, int relu) {
    int node = blockIdx.x * 8 + (threadIdx.x >> 5);
    int c4   = threadIdx.x & 31;
    if (node >= N_NODES) return;
    const float4* H4 = (const float4*)H;
    float di = dinv[node];
    float4 h = H4[(size_t)node * 32 + c4];
    float w0 = di * di;
    float4 acc = {h.x * w0, h.y * w0, h.z * w0, h.w * w0};
    int e0 = rowptr[node], e1 = rowptr[node + 1];
    int e = e0;
    for (; e + 3 < e1; e += 4) {
        int s0 = csr[e], s1 = csr[e + 1], s2 = csr[e + 2], s3 = csr[e + 3];
        float wa = dinv[s0] * di, wb = dinv[s1] * di;
        float wc = dinv[s2] * di, wd = dinv[s3] * di;
        float4 ha = H4[(size_t)s0 * 32 + c4];
        float4 hb = H4[(size_t)s1 * 32 + c4];
        float4 hc = H4[(size_t)s2 * 32 + c4];
        float4 hd = H4[(size_t)s3 * 32 + c4];
        acc.x += ha.x * wa + hb.x * wb + hc.x * wc + hd.x * wd;
        acc.y += ha.y * wa + hb.y * wb + hc.y * wc + hd.y * wd;
        acc.z += ha.z * wa + hb.z * wb + hc.z * wc + hd.z * wd;
        acc.w += ha.w * wa + hb.w * wb + hc.w * wc + hd.w * wd;
    }
    for (; e < e1; e++) {
        int s0 = csr[e];
        float wa = dinv[s0] * di;
        float4 ha = H4[(size_t)s0 * 32 + c4];
        acc.x += ha.x * wa; acc.y += ha.y * wa; acc.z += ha.z * wa; acc.w += ha.w * wa;
    }
    float4 b = ((const float4*)bias)[c4];
    float4 v = {acc.x + b.x, acc.y + b.y, acc.z + b.z, acc.w + b.w};
    if (relu) {
        v.x = fmaxf(v.x, 0.f); v.y = fmaxf(v.y, 0.f);
        v.z = fmaxf(v.z, 0.f); v.w = fmaxf(v.w, 0.f);
    }
    ((float4*)out)[(size_t)node * 32 + c4] = v;
}

// ---------------- Fused pool + head: batch is SORTED -> binary-search segments ----------------

__global__ __launch_bounds__(128) void k_pool_head(const float* __restrict__ h,
                                                   const int* __restrict__ batch,
                                                   const float* __restrict__ Wlin,
                                                   const float* __restrict__ blin,
                                                   float* __restrict__ out) {
    int g = blockIdx.x;
    int t = threadIdx.x;   // 128 threads, one channel each
    int lo = 0, hi = N_NODES;
    while (lo < hi) { int mid = (lo + hi) >> 1; if (batch[mid] < g) lo = mid + 1; else hi = mid; }
    int start = lo;
    hi = N_NODES;
    while (lo < hi) { int mid = (lo + hi) >> 1; if (batch[mid] < g + 1) lo = mid + 1; else hi = mid; }
    int end = lo;

    float acc = 0.f;
    int n = start;
    for (; n + 1 < end; n += 2)
        acc += h[(size_t)n * HID + t] + h[(size_t)(n + 1) * HID + t];
    if (n < end) acc += h[(size_t)n * HID + t];

    float inv = 1.0f / fmaxf((float)(end - start), 1.0f);
    float pooled = acc * inv;
    float p0 = pooled * Wlin[t * 2 + 0];
    float p1 = pooled * Wlin[t * 2 + 1];
    for (int o = 32; o; o >>= 1) { p0 += __shfl_down(p0, o); p1 += __shfl_down(p1, o); }
    __shared__ float r0s[2], r1s[2];
    int w = t >> 6;
    if ((t & 63) == 0) { r0s[w] = p0; r1s[w] = p1; }
    __syncthreads();
    if (t == 0) {
        out[g * 2 + 0] = r0s[0] + r0s[1] + blin[0];
        out[g * 2 + 1] = r1s[0] + r1s[1] + blin[1];
    }
}

// ---------------- launch ----------------

extern "C" void kernel_launch(void* const* d_in, const int* in_sizes, int n_in,
                              void* d_out, int out_size, void* d_ws, size_t ws_size,
                              hipStream_t stream) {
    const float* x    = (const float*)d_in[0];
    const float* W1   = (const float*)d_in[1];
    const float* b1   = (const float*)d_in[2];
    const float* W2   = (const float*)d_in[3];
    const float* b2   = (const float*)d_in[4];
    const float* W3   = (const float*)d_in[5];
    const float* b3   = (const float*)d_in[6];
    const float* Wlin = (const float*)d_in[7];
    const float* blin = (const float*)d_in[8];
    const int*   eidx = (const int*)d_in[9];
    const int*   batch= (const int*)d_in[10];
    const int* esrc = eidx;
    const int* edst = eidx + N_EDGES;
    float* out = (float*)d_out;

    char* w = (char*)d_ws;
    size_t off = 0;
    auto alloc = [&](size_t bytes) { size_t o = off; off = (off + bytes + 255) & ~(size_t)255; return o; };
    int*   cnt    = (int*)  (w + alloc(N_NODES * 4));
    int*   rowptr = (int*)  (w + alloc((N_NODES + 1) * 4));
    int*   csr    = (int*)  (w + alloc(N_EDGES * 4));
    float* dinv   = (float*)(w + alloc(N_NODES * 4));
    int*   bsum   = (int*)  (w + alloc(NB_SCAN * 4));
    float* s1     = (float*)(w + alloc(N_NODES * 4));
    float* hA     = (float*)(w + alloc((size_t)N_NODES * HID * 4));
    float* hB     = (float*)(w + alloc((size_t)N_NODES * HID * 4));

    const int EB = (N_EDGES + 255) / 256;       // 2344
    const int NB = (N_NODES + 255) / 256;       // 196

    // CSR + degrees
    hipMemsetAsync(cnt, 0, N_NODES * 4, stream);
    k_count<<<EB, 256, 0, stream>>>(edst, cnt);
    k_blocksum<<<NB_SCAN, 256, 0, stream>>>(cnt, bsum);
    k_scanbsum<<<1, 64, 0, stream>>>(bsum);
    k_rowptr<<<NB_SCAN, 256, 0, stream>>>(cnt, bsum, rowptr, dinv);
    hipMemsetAsync(cnt, 0, N_NODES * 4, stream);
    k_fill<<<EB, 256, 0, stream>>>(esrc, edst, rowptr, cnt, csr);

    dim3 gg((N_NODES + 63) / 64, 2);
    const int AB = (N_NODES + 7) / 8;           // 6250

    // Layer 1 (rank-1 shortcut)
    k_agg1<<<NB, 256, 0, stream>>>(x, rowptr, csr, dinv, s1);
    k_outer<<<(N_NODES * 32 + 255) / 256, 256, 0, stream>>>(s1, W1, b1, hB);
    // Layer 2
    k_gemm<<<gg, 256, 0, stream>>>(hB, W2, hA);
    k_agg<<<AB, 256, 0, stream>>>(hA, rowptr, csr, dinv, b2, hB, 1);
    // Layer 3
    k_gemm<<<gg, 256, 0, stream>>>(hB, W3, hA);
    k_agg<<<AB, 256, 0, stream>>>(hA, rowptr, csr, dinv, b3, hB, 0);

    // Fused pool + head
    k_pool_head<<<NG, 128, 0, stream>>>(hB, batch, Wlin, blin, out);
}

// Round 4
// 253.242 us; speedup vs baseline: 2.1783x; 1.4004x over previous
//
#include <hip/hip_runtime.h>
#include <hip/hip_bf16.h>

#define N_NODES 50000
#define N_EDGES 600000
#define HID     128
#define NG      500
#define NB_SCAN 196   // ceil(50000/256)
#define HSTP    65    // padded LDS leading dim

// ---------------- CSR build ----------------

__global__ void k_count(const int* __restrict__ dst, int* __restrict__ cnt) {
    int e = blockIdx.x * 256 + threadIdx.x;
    if (e < N_EDGES) atomicAdd(&cnt[dst[e]], 1);
}

__global__ void k_blocksum(const int* __restrict__ cnt, int* __restrict__ bsum) {
    __shared__ int s[256];
    int i = blockIdx.x * 256 + threadIdx.x;
    s[threadIdx.x] = (i < N_NODES) ? cnt[i] : 0;
    __syncthreads();
    for (int o = 128; o; o >>= 1) {
        if (threadIdx.x < o) s[threadIdx.x] += s[threadIdx.x + o];
        __syncthreads();
    }
    if (threadIdx.x == 0) bsum[blockIdx.x] = s[0];
}

__global__ void k_scanbsum(int* __restrict__ bsum) {
    int lane = threadIdx.x;            // 64 lanes
    int v[4];
    int base = lane * 4;
    for (int j = 0; j < 4; j++) v[j] = (base + j < NB_SCAN) ? bsum[base + j] : 0;
    int tot = v[0] + v[1] + v[2] + v[3];
    int inc = tot;
    for (int o = 1; o < 64; o <<= 1) {
        int u = __shfl_up(inc, o);
        if (lane >= o) inc += u;
    }
    int run = inc - tot;
    for (int j = 0; j < 4; j++) {
        if (base + j < NB_SCAN) bsum[base + j] = run;
        run += v[j];
    }
}

__global__ void k_rowptr(const int* __restrict__ cnt, const int* __restrict__ bsum,
                         int* __restrict__ rowptr, float* __restrict__ dinv) {
    __shared__ int s[256];
    int i = blockIdx.x * 256 + threadIdx.x;
    int c = (i < N_NODES) ? cnt[i] : 0;
    s[threadIdx.x] = c;
    __syncthreads();
    for (int o = 1; o < 256; o <<= 1) {
        int v = (threadIdx.x >= o) ? s[threadIdx.x - o] : 0;
        __syncthreads();
        s[threadIdx.x] += v;
        __syncthreads();
    }
    if (i < N_NODES) {
        int incl = s[threadIdx.x];
        rowptr[i] = bsum[blockIdx.x] + incl - c;
        dinv[i] = rsqrtf((float)c + 1.0f);
        if (i == N_NODES - 1) rowptr[N_NODES] = bsum[blockIdx.x] + incl;
    }
}

__global__ void k_fill(const int* __restrict__ src, const int* __restrict__ dst,
                       const int* __restrict__ rowptr, int* __restrict__ cnt,
                       int* __restrict__ csr) {
    int e = blockIdx.x * 256 + threadIdx.x;
    if (e < N_EDGES) {
        int d = dst[e];
        int pos = atomicAdd(&cnt[d], 1);
        csr[rowptr[d] + pos] = src[e];
    }
}

// ---------------- Layer 1: scalar aggregate of x (rank-1 input) ----------------

__global__ void k_agg1(const float* __restrict__ x, const int* __restrict__ rowptr,
                       const int* __restrict__ csr, const float* __restrict__ dinv,
                       float* __restrict__ s1) {
    int i = blockIdx.x * 256 + threadIdx.x;
    if (i >= N_NODES) return;
    float di = dinv[i];
    float acc = x[i] * di * di;
    int e0 = rowptr[i], e1 = rowptr[i + 1];
    int e = e0;
    for (; e + 3 < e1; e += 4) {
        int s0 = csr[e], s1i = csr[e+1], s2 = csr[e+2], s3 = csr[e+3];
        acc += x[s0]*dinv[s0]*di + x[s1i]*dinv[s1i]*di + x[s2]*dinv[s2]*di + x[s3]*dinv[s3]*di;
    }
    for (; e < e1; e++) {
        int s = csr[e];
        acc += x[s] * dinv[s] * di;
    }
    s1[i] = acc;
}

// ---------------- Precompute w3lin = W3 @ Wlin [128,2], c = b3@Wlin + blin ----------------

__global__ void k_w3lin(const float* __restrict__ W3, const float* __restrict__ Wlin,
                        const float* __restrict__ b3, const float* __restrict__ blin,
                        float* __restrict__ w3buf) {
    int t = threadIdx.x;          // 256 threads
    int k = t >> 1, j = t & 1;
    float acc = 0.f;
    for (int m = 0; m < 128; m++) acc += W3[k * 128 + m] * Wlin[m * 2 + j];
    w3buf[k * 2 + j] = acc;
    if (t < 2) {
        float c = 0.f;
        for (int m = 0; m < 128; m++) c += b3[m] * Wlin[m * 2 + t];
        w3buf[256 + t] = c + blin[t];   // constant added to every non-empty graph
        w3buf[258 + t] = blin[t];       // empty-graph fallback
    }
}

// ---------------- Fused layer-1-epilogue + layer-2 GEMM ----------------
// O[M,128] = relu(s1 ⊗ W1 + b1) @ W2.  A-tile generated in LDS from s1 (no h1 buffer).

__global__ __launch_bounds__(256) void k_gemm_l2(const float* __restrict__ s1,
                                                 const float* __restrict__ W1,
                                                 const float* __restrict__ b1,
                                                 const float* __restrict__ W2,
                                                 float* __restrict__ O) {
    __shared__ float Ws[128 * 64];       // 32 KB
    __shared__ float HsT[128 * HSTP];    // 33.3 KB, [k][r]
    int t  = threadIdx.x;
    int n0 = blockIdx.y * 64;
    int r0 = blockIdx.x * 64;

    for (int p = 0; p < 8; p++) {
        int elem = t * 4 + p * 1024;
        int k = elem >> 6, cc = elem & 63;
        *(float4*)&Ws[elem] = *(const float4*)&W2[k * 128 + n0 + cc];
    }
    // generate h1 tile transposed: HsT[k][r] = relu(s1[r0+r]*W1[k] + b1[k])
    int lane = t & 63, grp = t >> 6;     // 4 groups x 64 lanes
    int rr = r0 + lane;
    float sv = (rr < N_NODES) ? s1[rr] : 0.f;
    for (int kk = 0; kk < 32; kk++) {
        int k = grp * 32 + kk;
        HsT[k * HSTP + lane] = fmaxf(sv * W1[k] + b1[k], 0.f);
    }
    __syncthreads();

    int col = (t & 15) * 4;
    int row = (t >> 4) * 4;
    float acc[4][4] = {};
    #pragma unroll 4
    for (int k = 0; k < 128; k++) {
        float4 w = *(float4*)&Ws[k * 64 + col];
        float4 h = *(float4*)&HsT[k * HSTP + row];
        acc[0][0] += h.x * w.x; acc[0][1] += h.x * w.y; acc[0][2] += h.x * w.z; acc[0][3] += h.x * w.w;
        acc[1][0] += h.y * w.x; acc[1][1] += h.y * w.y; acc[1][2] += h.y * w.z; acc[1][3] += h.y * w.w;
        acc[2][0] += h.z * w.x; acc[2][1] += h.z * w.y; acc[2][2] += h.z * w.z; acc[2][3] += h.z * w.w;
        acc[3][0] += h.w * w.x; acc[3][1] += h.w * w.y; acc[3][2] += h.w * w.z; acc[3][3] += h.w * w.w;
    }
    for (int r = 0; r < 4; r++) {
        int rrr = r0 + row + r;
        if (rrr < N_NODES) {
            float4 v = {acc[r][0], acc[r][1], acc[r][2], acc[r][3]};
            *(float4*)&O[(size_t)rrr * HID + n0 + col] = v;
        }
    }
}

// ---------------- Fused layer-2 agg + relu + (·w3lin) projection to z[N,2] ----------------
// h2 is never materialized: each 32-lane group reduces its row against w3lin.

__global__ __launch_bounds__(256) void k_agg_fused(const float* __restrict__ H,
                                                   const int* __restrict__ rowptr,
                                                   const int* __restrict__ csr,
                                                   const float* __restrict__ dinv,
                                                   const float* __restrict__ b2,
                                                   const float* __restrict__ w3buf,
                                                   float* __restrict__ z) {
    int node = blockIdx.x * 8 + (threadIdx.x >> 5);   // grid exact: 6250*8 = 50000
    int c4   = threadIdx.x & 31;
    const float4* H4 = (const float4*)H;
    float di = dinv[node];
    float4 h = H4[(size_t)node * 32 + c4];
    float w0 = di * di;
    float4 acc = {h.x * w0, h.y * w0, h.z * w0, h.w * w0};
    int e0 = rowptr[node], e1 = rowptr[node + 1];
    int e = e0;
    for (; e + 7 < e1; e += 8) {
        int   si[8]; float wi[8]; float4 hi[8];
        #pragma unroll
        for (int j = 0; j < 8; j++) si[j] = csr[e + j];
        #pragma unroll
        for (int j = 0; j < 8; j++) wi[j] = dinv[si[j]] * di;
        #pragma unroll
        for (int j = 0; j < 8; j++) hi[j] = H4[(size_t)si[j] * 32 + c4];
        #pragma unroll
        for (int j = 0; j < 8; j++) {
            acc.x += hi[j].x * wi[j]; acc.y += hi[j].y * wi[j];
            acc.z += hi[j].z * wi[j]; acc.w += hi[j].w * wi[j];
        }
    }
    for (; e + 3 < e1; e += 4) {
        int s0 = csr[e], s1 = csr[e+1], s2 = csr[e+2], s3 = csr[e+3];
        float wa = dinv[s0]*di, wb = dinv[s1]*di, wc = dinv[s2]*di, wd = dinv[s3]*di;
        float4 ha = H4[(size_t)s0*32+c4], hb = H4[(size_t)s1*32+c4];
        float4 hc = H4[(size_t)s2*32+c4], hd = H4[(size_t)s3*32+c4];
        acc.x += ha.x*wa + hb.x*wb + hc.x*wc + hd.x*wd;
        acc.y += ha.y*wa + hb.y*wb + hc.y*wc + hd.y*wd;
        acc.z += ha.z*wa + hb.z*wb + hc.z*wc + hd.z*wd;
        acc.w += ha.w*wa + hb.w*wb + hc.w*wc + hd.w*wd;
    }
    for (; e < e1; e++) {
        int s0 = csr[e];
        float wa = dinv[s0] * di;
        float4 ha = H4[(size_t)s0 * 32 + c4];
        acc.x += ha.x*wa; acc.y += ha.y*wa; acc.z += ha.z*wa; acc.w += ha.w*wa;
    }
    float4 b = ((const float4*)b2)[c4];
    float4 v;
    v.x = fmaxf(acc.x + b.x, 0.f); v.y = fmaxf(acc.y + b.y, 0.f);
    v.z = fmaxf(acc.z + b.z, 0.f); v.w = fmaxf(acc.w + b.w, 0.f);
    // project: z[node] = v-row · w3lin  (w3buf layout [128][2])
    float4 wA = *(const float4*)&w3buf[c4 * 8];       // (w[4c4][0],w[4c4][1],w[4c4+1][0],w[4c4+1][1])
    float4 wB = *(const float4*)&w3buf[c4 * 8 + 4];
    float p0 = v.x * wA.x + v.y * wA.z + v.z * wB.x + v.w * wB.z;
    float p1 = v.x * wA.y + v.y * wA.w + v.z * wB.y + v.w * wB.w;
    for (int o = 16; o; o >>= 1) { p0 += __shfl_xor(p0, o); p1 += __shfl_xor(p1, o); }
    if (c4 == 0) { z[node * 2 + 0] = p0; z[node * 2 + 1] = p1; }
}

// ---------------- Layer-3 aggregation on z (2-wide) ----------------

__global__ void k_aggz(const float* __restrict__ z, const int* __restrict__ rowptr,
                       const int* __restrict__ csr, const float* __restrict__ dinv,
                       float* __restrict__ az) {
    int i = blockIdx.x * 256 + threadIdx.x;
    if (i >= N_NODES) return;
    const float2* Z = (const float2*)z;
    float di = dinv[i];
    float2 zi = Z[i];
    float a0 = zi.x * di * di, a1 = zi.y * di * di;
    int e0 = rowptr[i], e1 = rowptr[i + 1];
    int e = e0;
    for (; e + 3 < e1; e += 4) {
        int s0 = csr[e], s1 = csr[e+1], s2 = csr[e+2], s3 = csr[e+3];
        float w0 = dinv[s0]*di, w1 = dinv[s1]*di, w2 = dinv[s2]*di, w3 = dinv[s3]*di;
        float2 za = Z[s0], zb = Z[s1], zc = Z[s2], zd = Z[s3];
        a0 += za.x*w0 + zb.x*w1 + zc.x*w2 + zd.x*w3;
        a1 += za.y*w0 + zb.y*w1 + zc.y*w2 + zd.y*w3;
    }
    for (; e < e1; e++) {
        int s = csr[e];
        float w = dinv[s] * di;
        float2 za = Z[s];
        a0 += za.x * w; a1 += za.y * w;
    }
    float2 r = {a0, a1};
    ((float2*)az)[i] = r;
}

// ---------------- Final: per-graph mean of az + consts (batch sorted) ----------------

__global__ __launch_bounds__(64) void k_final2(const float* __restrict__ az,
                                               const int* __restrict__ batch,
                                               const float* __restrict__ w3buf,
                                               float* __restrict__ out) {
    int g = blockIdx.x;
    int lane = threadIdx.x;
    int lo = 0, hi = N_NODES;
    while (lo < hi) { int mid = (lo + hi) >> 1; if (batch[mid] < g) lo = mid + 1; else hi = mid; }
    int start = lo;
    hi = N_NODES;
    while (lo < hi) { int mid = (lo + hi) >> 1; if (batch[mid] < g + 1) lo = mid + 1; else hi = mid; }
    int end = lo;
    float a0 = 0.f, a1 = 0.f;
    for (int n = start + lane; n < end; n += 64) {
        float2 v = ((const float2*)az)[n];
        a0 += v.x; a1 += v.y;
    }
    for (int o = 32; o; o >>= 1) { a0 += __shfl_xor(a0, o); a1 += __shfl_xor(a1, o); }
    if (lane == 0) {
        if (end > start) {
            float inv = 1.0f / (float)(end - start);
            out[g * 2 + 0] = a0 * inv + w3buf[256];
            out[g * 2 + 1] = a1 * inv + w3buf[257];
        } else {
            out[g * 2 + 0] = w3buf[258];
            out[g * 2 + 1] = w3buf[259];
        }
    }
}

// ---------------- launch ----------------

extern "C" void kernel_launch(void* const* d_in, const int* in_sizes, int n_in,
                              void* d_out, int out_size, void* d_ws, size_t ws_size,
                              hipStream_t stream) {
    const float* x    = (const float*)d_in[0];
    const float* W1   = (const float*)d_in[1];
    const float* b1   = (const float*)d_in[2];
    const float* W2   = (const float*)d_in[3];
    const float* b2   = (const float*)d_in[4];
    const float* W3   = (const float*)d_in[5];
    const float* b3   = (const float*)d_in[6];
    const float* Wlin = (const float*)d_in[7];
    const float* blin = (const float*)d_in[8];
    const int*   eidx = (const int*)d_in[9];
    const int*   batch= (const int*)d_in[10];
    const int* esrc = eidx;
    const int* edst = eidx + N_EDGES;
    float* out = (float*)d_out;

    char* w = (char*)d_ws;
    size_t off = 0;
    auto alloc = [&](size_t bytes) { size_t o = off; off = (off + bytes + 255) & ~(size_t)255; return o; };
    int*   cnt    = (int*)  (w + alloc(N_NODES * 4));
    int*   rowptr = (int*)  (w + alloc((N_NODES + 1) * 4));
    int*   csr    = (int*)  (w + alloc(N_EDGES * 4));
    float* dinv   = (float*)(w + alloc(N_NODES * 4));
    int*   bsum   = (int*)  (w + alloc(NB_SCAN * 4));
    float* s1     = (float*)(w + alloc(N_NODES * 4));
    float* w3buf  = (float*)(w + alloc(260 * 4));
    float* t2     = (float*)(w + alloc((size_t)N_NODES * HID * 4));
    float* z      = (float*)(w + alloc((size_t)N_NODES * 2 * 4));
    float* az     = (float*)(w + alloc((size_t)N_NODES * 2 * 4));

    const int EB = (N_EDGES + 255) / 256;       // 2344
    const int NB = (N_NODES + 255) / 256;       // 196

    // CSR + degrees
    hipMemsetAsync(cnt, 0, N_NODES * 4, stream);
    k_count<<<EB, 256, 0, stream>>>(edst, cnt);
    k_blocksum<<<NB_SCAN, 256, 0, stream>>>(cnt, bsum);
    k_scanbsum<<<1, 64, 0, stream>>>(bsum);
    k_rowptr<<<NB_SCAN, 256, 0, stream>>>(cnt, bsum, rowptr, dinv);
    hipMemsetAsync(cnt, 0, N_NODES * 4, stream);
    k_fill<<<EB, 256, 0, stream>>>(esrc, edst, rowptr, cnt, csr);

    // scalar layer-1 aggregate + head-weight precompute
    k_agg1<<<NB, 256, 0, stream>>>(x, rowptr, csr, dinv, s1);
    k_w3lin<<<1, 256, 0, stream>>>(W3, Wlin, b3, blin, w3buf);

    // fused layer1-epilogue + layer2 GEMM
    dim3 gg((N_NODES + 63) / 64, 2);
    k_gemm_l2<<<gg, 256, 0, stream>>>(s1, W1, b1, W2, t2);

    // fused layer2 agg+relu+projection -> z [N,2]
    k_agg_fused<<<(N_NODES + 7) / 8, 256, 0, stream>>>(t2, rowptr, csr, dinv, b2, w3buf, z);

    // layer3 2-wide aggregation + per-graph mean + consts
    k_aggz<<<NB, 256, 0, stream>>>(z, rowptr, csr, dinv, az);
    k_final2<<<NG, 64, 0, stream>>>(az, batch, w3buf, out);
}